// Round 8
// baseline (1009.693 us; speedup 1.0000x reference)
//
#include <hip/hip_runtime.h>

constexpr int NN = 150000;   // nodes
constexpr int NE = 4800000;  // edges
constexpr int NG = 512;      // graphs
constexpr int H  = 16;       // hidden
constexpr int NB   = 1024;   // coarse dst-buckets
constexpr int NPBK = 147;    // nodes per bucket (ceil NN/NB)
constexpr int NBLK = 256;    // streaming blocks for hist/bucket
constexpr int CHUNK = (NE + NBLK - 1) / NBLK;   // 18750 edges per block

// ---------- phase A: per-block LDS histogram of dst buckets ----------
__global__ void k_hist(const int* __restrict__ dst, int* __restrict__ mat) {
    __shared__ int cnt[NB];
    for (int t = threadIdx.x; t < NB; t += 256) cnt[t] = 0;
    __syncthreads();
    int b = blockIdx.x;
    int e0 = b * CHUNK, e1 = min(e0 + CHUNK, NE);
    for (int e = e0 + (int)threadIdx.x; e < e1; e += 256)
        atomicAdd(&cnt[dst[e] / NPBK], 1);
    __syncthreads();
    for (int t = threadIdx.x; t < NB; t += 256) mat[b * NB + t] = cnt[t];
}

// ---------- column scan: mat[:,j] -> exclusive prefix, totals ----------
__global__ void k_scanb(int* __restrict__ mat, int* __restrict__ tot) {
    __shared__ int tmp[NBLK];
    int j = blockIdx.x, t = threadIdx.x;
    int v = mat[t * NB + j];
    tmp[t] = v;
    __syncthreads();
    for (int off = 1; off < NBLK; off <<= 1) {
        int a = (t >= off) ? tmp[t - off] : 0;
        __syncthreads();
        tmp[t] += a;
        __syncthreads();
    }
    mat[t * NB + j] = tmp[t] - v;               // exclusive within column
    if (t == NBLK - 1) tot[j] = tmp[t];
}

// ---------- bucket base scan (exclusive over 1024 buckets) ----------
__global__ void k_scant(const int* __restrict__ tot, int* __restrict__ base) {
    __shared__ int tmp[NB];
    int t = threadIdx.x;
    int v = tot[t];
    tmp[t] = v;
    __syncthreads();
    for (int off = 1; off < NB; off <<= 1) {
        int a = (t >= off) ? tmp[t - off] : 0;
        __syncthreads();
        tmp[t] += a;
        __syncthreads();
    }
    base[t] = tmp[t] - v;
    if (t == 0) base[NB] = NE;
}

// ---------- phase B: write (src,dst) grouped by bucket, LDS cursors ----------
__global__ void k_bucket(const int* __restrict__ src, const int* __restrict__ dst,
                         const int* __restrict__ mat, const int* __restrict__ base,
                         uint2* __restrict__ ed) {
    __shared__ int cur[NB];
    int b = blockIdx.x;
    for (int t = threadIdx.x; t < NB; t += 256) cur[t] = base[t] + mat[b * NB + t];
    __syncthreads();
    int e0 = b * CHUNK, e1 = min(e0 + CHUNK, NE);
    for (int e = e0 + (int)threadIdx.x; e < e1; e += 256) {
        int d = dst[e];
        int p = atomicAdd(&cur[d / NPBK], 1);
        ed[p] = make_uint2((unsigned)src[e], (unsigned)d);
    }
}

// ---------- per-bucket degree -> disq (LDS count) ----------
__global__ void k_disq_b(const uint2* __restrict__ ed, const int* __restrict__ base,
                         float* __restrict__ disq) {
    __shared__ int cnt[NPBK];
    int j = blockIdx.x;
    for (int t = threadIdx.x; t < NPBK; t += 256) cnt[t] = 0;
    __syncthreads();
    int n0 = j * NPBK;
    int e0 = base[j], e1 = base[j + 1];
    for (int e = e0 + (int)threadIdx.x; e < e1; e += 256)
        atomicAdd(&cnt[(int)ed[e].y - n0], 1);
    __syncthreads();
    for (int t = threadIdx.x; t < NPBK; t += 256) {
        int n = n0 + t;
        if (n < NN) disq[n] = rsqrtf((float)(cnt[t] + 1));
    }
}

// ---------- y = (x @ W1) * disq ----------
__global__ void k_xw1(const float* __restrict__ x, const float* __restrict__ W1,
                      const float* __restrict__ disq, float* __restrict__ y) {
    __shared__ float w[4 * H];
    if (threadIdx.x < 4 * H) w[threadIdx.x] = W1[threadIdx.x];
    __syncthreads();
    int i = blockIdx.x * blockDim.x + threadIdx.x;
    if (i >= NN) return;
    float4 xv = ((const float4*)x)[i];
    float d = disq[i];
    float o[H];
#pragma unroll
    for (int h = 0; h < H; ++h)
        o[h] = (xv.x * w[0*H + h] + xv.y * w[1*H + h] +
                xv.z * w[2*H + h] + xv.w * w[3*H + h]) * d;
    float4* yp = (float4*)(y + (size_t)i * H);
#pragma unroll
    for (int q = 0; q < 4; ++q) yp[q] = ((float4*)o)[q];
}

// ---------- phase C: per-bucket LDS accumulate + fused epilogue ----------
// h[n] = relu(disq[n] * (y[n] + sum_{e:dst=n} y[src_e]) + b)
__global__ void k_conv(const uint2* __restrict__ ed, const int* __restrict__ base,
                       const float* __restrict__ y, const float* __restrict__ disq,
                       const float* __restrict__ bias, float* __restrict__ hout) {
    __shared__ float acc[NPBK * H];     // 9408 B
    __shared__ float bs[H];
    if (threadIdx.x < H) bs[threadIdx.x] = bias[threadIdx.x];
    for (int t = threadIdx.x; t < NPBK * H; t += 256) acc[t] = 0.f;
    __syncthreads();
    int j = blockIdx.x;
    int n0 = j * NPBK;
    int e0 = base[j], e1 = base[j + 1];
    int lane = threadIdx.x & (H - 1);
    int grp  = threadIdx.x >> 4;        // 16 edge-groups per block
    for (int e = e0 + grp; e < e1; e += 16) {
        uint2 ee = ed[e];
        float v = y[(size_t)ee.x * H + lane];
        atomicAdd(&acc[((int)ee.y - n0) * H + lane], v);
    }
    __syncthreads();
    for (int t = grp; t < NPBK; t += 16) {
        int n = n0 + t;
        if (n >= NN) break;
        float a = acc[t * H + lane] + y[(size_t)n * H + lane];
        hout[(size_t)n * H + lane] = fmaxf(fmaf(a, disq[n], bs[lane]), 0.f);
    }
}

// ---------- y = (h @ W2) * disq ----------
__global__ void k_hw2(const float* __restrict__ hin, const float* __restrict__ W2,
                      const float* __restrict__ disq, float* __restrict__ yout) {
    __shared__ float w[H * H];
    if (threadIdx.x < H * H) w[threadIdx.x] = W2[threadIdx.x];
    __syncthreads();
    int i = blockIdx.x * blockDim.x + threadIdx.x;
    if (i >= NN) return;
    float hv[H];
    const float4* hp = (const float4*)(hin + (size_t)i * H);
#pragma unroll
    for (int q = 0; q < 4; ++q) ((float4*)hv)[q] = hp[q];
    float d = disq[i];
    float o[H];
#pragma unroll
    for (int h = 0; h < H; ++h) {
        float s = 0.f;
#pragma unroll
        for (int k = 0; k < H; ++k) s += hv[k] * w[k*H + h];
        o[h] = s * d;
    }
    float4* yp = (float4*)(yout + (size_t)i * H);
#pragma unroll
    for (int q = 0; q < 4; ++q) yp[q] = ((float4*)o)[q];
}

// ---------- pool: batch sorted -> binary-search segmented sum ----------
__global__ void k_pool_seg(const float* __restrict__ h, const int* __restrict__ batch,
                           float* __restrict__ gout) {
    int g    = blockIdx.x * (blockDim.x / H) + threadIdx.x / H;
    int lane = threadIdx.x & (H - 1);
    if (g >= NG) return;
    int lo = 0, hi = NN;
    while (lo < hi) { int m = (lo + hi) >> 1; if (batch[m] < g) lo = m + 1; else hi = m; }
    int start = lo;
    hi = NN;
    while (lo < hi) { int m = (lo + hi) >> 1; if (batch[m] < g + 1) lo = m + 1; else hi = m; }
    int end = lo;
    float acc = 0.f;
    for (int i = start; i < end; ++i) acc += h[(size_t)i * H + lane];
    gout[(size_t)g * H + lane] = acc;
}

// ---------- final MLP ----------
__global__ void k_mlp(const float* __restrict__ g, const float* __restrict__ Wf1,
                      const float* __restrict__ bf1, const float* __restrict__ Wf2,
                      const float* __restrict__ bf2, float* __restrict__ out) {
    __shared__ float w1[H * H];
    __shared__ float b1s[H];
    __shared__ float w2[H];
    __shared__ float b2s;
    if (threadIdx.x < H * H) w1[threadIdx.x] = Wf1[threadIdx.x];
    if (threadIdx.x < H) { b1s[threadIdx.x] = bf1[threadIdx.x]; w2[threadIdx.x] = Wf2[threadIdx.x]; }
    if (threadIdx.x == 0) b2s = bf2[0];
    __syncthreads();
    int i = blockIdx.x * blockDim.x + threadIdx.x;
    if (i >= NG) return;
    float gv[H];
    const float4* gp = (const float4*)(g + (size_t)i * H);
#pragma unroll
    for (int q = 0; q < 4; ++q) ((float4*)gv)[q] = gp[q];
    float s2 = 0.f;
#pragma unroll
    for (int h = 0; h < H; ++h) {
        float t = b1s[h];
#pragma unroll
        for (int k = 0; k < H; ++k) t += gv[k] * w1[k*H + h];
        s2 += fmaxf(t, 0.f) * w2[h];
    }
    out[i] = s2 + b2s;
}

// ================= fallback (baseline atomic path) =================
__global__ void k_deg_init(float* __restrict__ deg) {
    int i = blockIdx.x * blockDim.x + threadIdx.x;
    if (i < NN) deg[i] = 1.0f;
}
__global__ void k_deg_edges(const int* __restrict__ dst, float* __restrict__ deg) {
    int i = blockIdx.x * blockDim.x + threadIdx.x;
    if (i < NE) atomicAdd(&deg[dst[i]], 1.0f);
}
__global__ void k_disq(float* __restrict__ deg) {
    int i = blockIdx.x * blockDim.x + threadIdx.x;
    if (i < NN) deg[i] = rsqrtf(deg[i]);
}
__global__ void k_scatter(const int* __restrict__ src, const int* __restrict__ dst,
                          const float* __restrict__ y, float* __restrict__ acc) {
    int i = blockIdx.x * blockDim.x + threadIdx.x;
    if (i >= NE) return;
    int s = src[i], d = dst[i];
    const float4* yp = (const float4*)(y + (size_t)s * H);
    float* ap = acc + (size_t)d * H;
#pragma unroll
    for (int q = 0; q < 4; ++q) {
        float4 v = yp[q];
        atomicAdd(ap + q*4 + 0, v.x);
        atomicAdd(ap + q*4 + 1, v.y);
        atomicAdd(ap + q*4 + 2, v.z);
        atomicAdd(ap + q*4 + 3, v.w);
    }
}
__global__ void k_post(const float* __restrict__ acc, const float* __restrict__ disq,
                       const float* __restrict__ b, float* __restrict__ hout) {
    __shared__ float bs[H];
    if (threadIdx.x < H) bs[threadIdx.x] = b[threadIdx.x];
    __syncthreads();
    int i = blockIdx.x * blockDim.x + threadIdx.x;
    if (i >= NN) return;
    float d = disq[i];
    const float4* ap = (const float4*)(acc + (size_t)i * H);
    float4* hp = (float4*)(hout + (size_t)i * H);
#pragma unroll
    for (int q = 0; q < 4; ++q) {
        float4 v = ap[q];
        float4 r;
        r.x = fmaxf(v.x * d + bs[q*4+0], 0.f);
        r.y = fmaxf(v.y * d + bs[q*4+1], 0.f);
        r.z = fmaxf(v.z * d + bs[q*4+2], 0.f);
        r.w = fmaxf(v.w * d + bs[q*4+3], 0.f);
        hp[q] = r;
    }
}

extern "C" void kernel_launch(void* const* d_in, const int* in_sizes, int n_in,
                              void* d_out, int out_size, void* d_ws, size_t ws_size,
                              hipStream_t stream) {
    const float* x   = (const float*)d_in[0];
    const float* W1  = (const float*)d_in[1];
    const float* b1  = (const float*)d_in[2];
    const float* W2  = (const float*)d_in[3];
    const float* b2  = (const float*)d_in[4];
    const float* Wf1 = (const float*)d_in[5];
    const float* bf1 = (const float*)d_in[6];
    const float* Wf2 = (const float*)d_in[7];
    const float* bf2 = (const float*)d_in[8];
    const int*   ei    = (const int*)d_in[9];
    const int*   batch = (const int*)d_in[10];
    const int* src = ei;        // edge_index row 0
    const int* dst = ei + NE;   // edge_index row 1
    float* out = (float*)d_out;

    const int BT  = 256;
    const int gbN = (NN + BT - 1) / BT;               // 586
    const int gbE = (NE + BT - 1) / BT;               // 18750 (fallback)
    const int NPB = BT / H;                           // 16
    const int gbP = (NG + NPB - 1) / NPB;             // 32

    // ---- workspace layout (4-byte units; region starts 16B-aligned) ----
    // mat[256*1024] | tot[1024] | base[1025]pad | ed[2*NE] (uint2) |
    // disq[NN] | bufA[NN*H] | bufB[NN*H] | g[NG*H]
    size_t need = ((size_t)14822400) * 4;   // ~59.3 MB
    if (ws_size >= need) {
        int*   mat  = (int*)d_ws;                  // 262144
        int*   tot  = mat + 262144;                // 1024
        int*   base = mat + 263168;                // 1025 (pad to 264208)
        uint2* ed   = (uint2*)(mat + 264208);      // 4.8M uint2
        float* disq = (float*)(mat + 9864208);
        float* bufA = (float*)(mat + 10014208);
        float* bufB = (float*)(mat + 12414208);
        float* g    = (float*)(mat + 14814208);

        // graph bucketing (no global atomics)
        k_hist  <<<NBLK, 256, 0, stream>>>(dst, mat);
        k_scanb <<<NB,   NBLK, 0, stream>>>(mat, tot);
        k_scant <<<1,    NB,  0, stream>>>(tot, base);
        k_bucket<<<NBLK, 256, 0, stream>>>(src, dst, mat, base, ed);
        k_disq_b<<<NB,   256, 0, stream>>>(ed, base, disq);

        // conv1
        k_xw1 <<<gbN, 256, 0, stream>>>(x, W1, disq, bufA);
        k_conv<<<NB,  256, 0, stream>>>(ed, base, bufA, disq, b1, bufB);   // h1
        // conv2
        k_hw2 <<<gbN, 256, 0, stream>>>(bufB, W2, disq, bufA);             // y2
        k_conv<<<NB,  256, 0, stream>>>(ed, base, bufA, disq, b2, bufB);   // h2
        // pool + MLP
        k_pool_seg<<<gbP, 256, 0, stream>>>(bufB, batch, g);
        k_mlp<<<1, 512, 0, stream>>>(g, Wf1, bf1, Wf2, bf2, out);
    } else {
        // fallback: baseline atomic-scatter path (~20 MB ws)
        float* disq = (float*)d_ws;
        float* bufA = disq + NN;
        float* bufB = bufA + (size_t)NN * H;
        float* g    = bufB + (size_t)NN * H;

        k_deg_init<<<gbN, BT, 0, stream>>>(disq);
        k_deg_edges<<<gbE, BT, 0, stream>>>(dst, disq);
        k_disq<<<gbN, BT, 0, stream>>>(disq);

        k_xw1<<<gbN, BT, 0, stream>>>(x, W1, disq, bufA);
        hipMemcpyAsync(bufB, bufA, (size_t)NN * H * sizeof(float),
                       hipMemcpyDeviceToDevice, stream);
        k_scatter<<<gbE, BT, 0, stream>>>(src, dst, bufA, bufB);
        k_post<<<gbN, BT, 0, stream>>>(bufB, disq, b1, bufA);

        k_hw2<<<gbN, BT, 0, stream>>>(bufA, W2, disq, bufB);
        hipMemcpyAsync(bufA, bufB, (size_t)NN * H * sizeof(float),
                       hipMemcpyDeviceToDevice, stream);
        k_scatter<<<gbE, BT, 0, stream>>>(src, dst, bufB, bufA);
        k_post<<<gbN, BT, 0, stream>>>(bufA, disq, b2, bufB);

        k_pool_seg<<<gbP, BT, 0, stream>>>(bufB, batch, g);
        k_mlp<<<1, 512, 0, stream>>>(g, Wf1, bf1, Wf2, bf2, out);
    }
}